// Round 2
// baseline (542.756 us; speedup 1.0000x reference)
//
#include <hip/hip_runtime.h>
#include <hip/hip_bf16.h>

#define K_IN 2624     // 2048 + 512 + 64
#define NSTEP 82      // K-steps of 32

typedef __attribute__((ext_vector_type(8))) short short8;
typedef __attribute__((ext_vector_type(4))) float float4_t;

__device__ __forceinline__ short f2bf(float f) {
    union { __hip_bfloat16 b; short s; } u;
    u.b = __float2bfloat16(f);
    return u.s;
}

__device__ __forceinline__ float sigmoid_fast(float x) {
    return 1.f / (1.f + __expf(-x));
}

__device__ __forceinline__ float tanh_fast(float x) {
    float e = __expf(-2.f * fabsf(x));
    float t = (1.f - e) / (1.f + e);
    return copysignf(t, x);
}

// ---------------------------------------------------------------------------
// prep: pack fused weight [Wi;Wh] (K_IN x 256, fp32, k-major) into
// MFMA-B-fragment order, bf16:
//   Wt2 laid out as [kstep s][nb][lane][8elem], so one wave B-frag load is a
//   contiguous 1KB global_load_dwordx4 (lane l holds B[k=s*32+(l>>4)*8+j][n=nb*16+(l&15)]).
// Also bsum[n] = bi[n]+bh[n].
// grid: 82 blocks x 256 threads.
// ---------------------------------------------------------------------------
__global__ void prep_kernel(const float* __restrict__ Wi, const float* __restrict__ bi,
                            const float* __restrict__ Wh, const float* __restrict__ bh,
                            short* __restrict__ Wt2, float* __restrict__ bsum) {
    __shared__ short tile[32][264];   // +8 pad
    const int t = threadIdx.x;
    const int kb = blockIdx.x;
    const int k0 = kb * 32;

#pragma unroll 8
    for (int j = 0; j < 32; ++j) {
        int k = k0 + j;
        float v = (k < 2560) ? Wi[(size_t)k * 256 + t]
                             : Wh[(size_t)(k - 2560) * 256 + t];
        tile[j][t] = f2bf(v);
    }
    if (kb == 0) bsum[t] = bi[t] + bh[t];
    __syncthreads();

#pragma unroll
    for (int c = 0; c < 4; ++c) {
        int idx = c * 256 + t;          // 0..1023 = nb*64 + lane
        int lane = idx & 63;
        int nb = idx >> 6;
        int n = nb * 16 + (lane & 15);
        int j0 = (lane >> 4) * 8;
        short8 v;
#pragma unroll
        for (int j = 0; j < 8; ++j) v[j] = tile[j0 + j][n];
        *reinterpret_cast<short8*>(Wt2 + (size_t)kb * 8192 + (size_t)idx * 8) = v;
    }
}

// ---------------------------------------------------------------------------
// Barrier-free fused GEMM + LSTM.
// 1 wave per block; wave owns 16 batch rows x all 256 gate cols.
// A: direct global->reg (fp32 stream, nontemporal), cvt to bf16 in regs.
// B: fragment-order global loads (L1/L2-resident weights), 1KB/inst.
// Manual 1-kstep register double-buffer; NO __syncthreads in the K-loop.
// ---------------------------------------------------------------------------
__global__ __launch_bounds__(64, 2)
void lstm_kernel(const float* __restrict__ state, const float* __restrict__ action,
                 const float* __restrict__ hidden, const float* __restrict__ cell,
                 const short* __restrict__ Wt2, const float* __restrict__ bsum,
                 const float* __restrict__ Wo, const float* __restrict__ bo,
                 float* __restrict__ out, int Brows) {
    __shared__ float sG[16 * 260];

    const int l = threadIdx.x;
    const int bm = blockIdx.x;
    const int lr = l & 15;
    const int q = l >> 4;

    const size_t mrow = (size_t)bm * 16 + lr;
    const float* aS = state  + mrow * 2048 + q * 8;
    const float* aA = action + mrow * 512  + q * 8;
    const float* aH = hidden + mrow * 64   + q * 8;
    const short* bP = Wt2 + (size_t)l * 8;

    float4_t acc[16];
#pragma unroll
    for (int nb = 0; nb < 16; ++nb) acc[nb] = (float4_t)(0.f);

    // preload k-step 0
    short8 Bc[16];
    float4_t Ac0, Ac1;
#pragma unroll
    for (int nb = 0; nb < 16; ++nb)
        Bc[nb] = *reinterpret_cast<const short8*>(bP + nb * 512);
    Ac0 = __builtin_nontemporal_load(reinterpret_cast<const float4_t*>(aS));
    Ac1 = __builtin_nontemporal_load(reinterpret_cast<const float4_t*>(aS + 4));

#pragma unroll 2
    for (int s = 0; s < 81; ++s) {
        // ---- prefetch k-step s+1 ----
        short8 Bn[16];
        float4_t An0, An1;
        const short* bp1 = bP + (size_t)(s + 1) * 8192;
#pragma unroll
        for (int nb = 0; nb < 16; ++nb)
            Bn[nb] = *reinterpret_cast<const short8*>(bp1 + nb * 512);
        {
            int sn = s + 1;
            const float* p;
            int col;
            if (sn < 64)      { p = aS; col = sn * 32; }
            else if (sn < 80) { p = aA; col = (sn - 64) * 32; }
            else              { p = aH; col = (sn - 80) * 32; }
            An0 = __builtin_nontemporal_load(reinterpret_cast<const float4_t*>(p + col));
            An1 = __builtin_nontemporal_load(reinterpret_cast<const float4_t*>(p + col + 4));
        }

        // ---- compute k-step s ----
        short8 a;
        a[0] = f2bf(Ac0[0]); a[1] = f2bf(Ac0[1]); a[2] = f2bf(Ac0[2]); a[3] = f2bf(Ac0[3]);
        a[4] = f2bf(Ac1[0]); a[5] = f2bf(Ac1[1]); a[6] = f2bf(Ac1[2]); a[7] = f2bf(Ac1[3]);
#pragma unroll
        for (int nb = 0; nb < 16; ++nb)
            acc[nb] = __builtin_amdgcn_mfma_f32_16x16x32_bf16(a, Bc[nb], acc[nb], 0, 0, 0);

        // rotate (renamed away by unroll-2)
#pragma unroll
        for (int nb = 0; nb < 16; ++nb) Bc[nb] = Bn[nb];
        Ac0 = An0; Ac1 = An1;
    }
    {   // final k-step 81
        short8 a;
        a[0] = f2bf(Ac0[0]); a[1] = f2bf(Ac0[1]); a[2] = f2bf(Ac0[2]); a[3] = f2bf(Ac0[3]);
        a[4] = f2bf(Ac1[0]); a[5] = f2bf(Ac1[1]); a[6] = f2bf(Ac1[2]); a[7] = f2bf(Ac1[3]);
#pragma unroll
        for (int nb = 0; nb < 16; ++nb)
            acc[nb] = __builtin_amdgcn_mfma_f32_16x16x32_bf16(a, Bc[nb], acc[nb], 0, 0, 0);
    }

    // ---- epilogue: gates -> LDS transpose -> LSTM -> h@Wo ----
    // C-layout: row = q*4 + r, col = nb*16 + lr
#pragma unroll
    for (int nb = 0; nb < 16; ++nb)
#pragma unroll
        for (int r = 0; r < 4; ++r)
            sG[(q * 4 + r) * 260 + nb * 16 + lr] = acc[nb][r];
    __syncthreads();

    const float wo = Wo[l];
    const float bov = bo[0];
    const float b0 = bsum[l];
    const float b1 = bsum[64 + l];
    const float b2 = bsum[128 + l];
    const float b3 = bsum[192 + l];
    float* outH = out + Brows;
    float* outC = outH + (size_t)Brows * 64;

#pragma unroll
    for (int r = 0; r < 16; ++r) {
        size_t grow = (size_t)bm * 16 + r;
        float gi = sG[r * 260 + l]       + b0;
        float gf = sG[r * 260 + 64 + l]  + b1;
        float gg = sG[r * 260 + 128 + l] + b2;
        float go = sG[r * 260 + 192 + l] + b3;
        float i_t = sigmoid_fast(gi);
        float f_t = sigmoid_fast(gf);
        float g_t = tanh_fast(gg);
        float o_t = sigmoid_fast(go);
        float c_t = f_t * cell[grow * 64 + l] + i_t * g_t;
        float h_t = o_t * tanh_fast(c_t);
        outC[grow * 64 + l] = c_t;
        outH[grow * 64 + l] = h_t;
        float v = h_t * wo;
#pragma unroll
        for (int off = 32; off > 0; off >>= 1) v += __shfl_down(v, off);
        if (l == 0) out[grow] = tanh_fast(v + bov);
    }
}

extern "C" void kernel_launch(void* const* d_in, const int* in_sizes, int n_in,
                              void* d_out, int out_size, void* d_ws, size_t ws_size,
                              hipStream_t stream) {
    const float* state  = (const float*)d_in[0];
    const float* action = (const float*)d_in[1];
    const float* hidden = (const float*)d_in[2];
    const float* cell   = (const float*)d_in[3];
    const float* Wi     = (const float*)d_in[4];
    const float* bi     = (const float*)d_in[5];
    const float* Wh     = (const float*)d_in[6];
    const float* bh     = (const float*)d_in[7];
    const float* Wo     = (const float*)d_in[8];
    const float* bo     = (const float*)d_in[9];

    const int Brows = in_sizes[0] / 2048;   // 32768

    short* Wt2  = (short*)d_ws;                                    // 82*8192 bf16
    float* bsum = (float*)((char*)d_ws + (size_t)NSTEP * 8192 * sizeof(short));

    prep_kernel<<<NSTEP, 256, 0, stream>>>(Wi, bi, Wh, bh, Wt2, bsum);
    lstm_kernel<<<Brows / 16, 64, 0, stream>>>(state, action, hidden, cell,
                                               Wt2, bsum, Wo, bo, (float*)d_out, Brows);
}

// Round 3
// 460.574 us; speedup vs baseline: 1.1784x; 1.1784x over previous
//
#include <hip/hip_runtime.h>
#include <hip/hip_bf16.h>

#define K_IN 2624     // 2048 + 512 + 64
#define NSTEP 82      // K-steps of 32 (prep granularity)
#define NCHUNK 41     // K-chunks of 64 (lstm granularity)

typedef __attribute__((ext_vector_type(8))) short short8;
typedef __attribute__((ext_vector_type(4))) float float4_t;

__device__ __forceinline__ short f2bf(float f) {
    union { __hip_bfloat16 b; short s; } u;
    u.b = __float2bfloat16(f);
    return u.s;
}

__device__ __forceinline__ float sigmoid_fast(float x) {
    return 1.f / (1.f + __expf(-x));
}

__device__ __forceinline__ float tanh_fast(float x) {
    float e = __expf(-2.f * fabsf(x));
    float t = (1.f - e) / (1.f + e);
    return copysignf(t, x);
}

// ---------------------------------------------------------------------------
// prep: pack fused weight [Wi;Wh] (K_IN x 256, fp32, k-major) into
// MFMA-B-fragment order, bf16:
//   Wt2[kstep s][nb][lane][8elem]: lane l holds B[k=s*32+(l>>4)*8+j][n=nb*16+(l&15)].
// Also bsum[n] = bi[n]+bh[n].
// ---------------------------------------------------------------------------
__global__ void prep_kernel(const float* __restrict__ Wi, const float* __restrict__ bi,
                            const float* __restrict__ Wh, const float* __restrict__ bh,
                            short* __restrict__ Wt2, float* __restrict__ bsum) {
    __shared__ short tile[32][264];   // +8 pad
    const int t = threadIdx.x;
    const int kb = blockIdx.x;
    const int k0 = kb * 32;

#pragma unroll 8
    for (int j = 0; j < 32; ++j) {
        int k = k0 + j;
        float v = (k < 2560) ? Wi[(size_t)k * 256 + t]
                             : Wh[(size_t)(k - 2560) * 256 + t];
        tile[j][t] = f2bf(v);
    }
    if (kb == 0) bsum[t] = bi[t] + bh[t];
    __syncthreads();

#pragma unroll
    for (int c = 0; c < 4; ++c) {
        int idx = c * 256 + t;          // 0..1023 = nb*64 + lane
        int lane = idx & 63;
        int nb = idx >> 6;
        int n = nb * 16 + (lane & 15);
        int j0 = (lane >> 4) * 8;
        short8 v;
#pragma unroll
        for (int j = 0; j < 8; ++j) v[j] = tile[j0 + j][n];
        *reinterpret_cast<short8*>(Wt2 + (size_t)kb * 8192 + (size_t)idx * 8) = v;
    }
}

// ---------------------------------------------------------------------------
// Fused GEMM + LSTM, round 3.
// 512 blocks x 256 threads (4 waves). Block owns 64 batch rows; wave w owns
// rows [bm*64 + w*16, +16) x all 256 gate cols (16 n-frags, acc = 64 VGPRs).
// A: per-wave global->reg, prefetched ONE chunk ahead (at barrier time the
//    newest A load is ~a full body old -> vmcnt(0) drain is cheap).
// B: global->reg (8 float4/thread, L2-resident) -> ds_write into a BK=64
//    double buffer (2 x 32KB LDS). ONE __syncthreads per chunk.
// ---------------------------------------------------------------------------
__global__ __launch_bounds__(256, 2)
void lstm_kernel(const float* __restrict__ state, const float* __restrict__ action,
                 const float* __restrict__ hidden, const float* __restrict__ cell,
                 const short* __restrict__ Wt2, const float* __restrict__ bsum,
                 const float* __restrict__ Wo, const float* __restrict__ bo,
                 float* __restrict__ out, int Brows) {
    __shared__ __align__(16) short sB[2 * 16384];   // 64 KB: two 64x256 bf16 chunks

    const int t = threadIdx.x;
    const int w = t >> 6;
    const int l = t & 63;
    const int lr = l & 15;
    const int q = l >> 4;
    const int bm = blockIdx.x;

    // A row for this lane (frag m-index = lr)
    const size_t mrow = (size_t)bm * 64 + w * 16 + lr;
    const float* aS = state  + mrow * 2048;
    const float* aA = action + mrow * 512;
    const float* aH = hidden + mrow * 64;

    // B global base: thread t reads 8 x 16B per chunk, contiguous layout
    const short* bg = Wt2 + t * 8;

    float4_t acc[16];
#pragma unroll
    for (int nb = 0; nb < 16; ++nb) acc[nb] = (float4_t)(0.f);

    float4_t aCur[4], aNxt[4], bReg[8];

    // helper lambdas (inlined)
    auto loadA = [&](int c, float4_t* dst) {
        const float* p; int col;
        if (c < 32)      { p = aS; col = c * 64; }
        else if (c < 40) { p = aA; col = (c - 32) * 64; }
        else             { p = aH; col = 0; }
        dst[0] = *reinterpret_cast<const float4_t*>(p + col + q * 8);
        dst[1] = *reinterpret_cast<const float4_t*>(p + col + q * 8 + 4);
        dst[2] = *reinterpret_cast<const float4_t*>(p + col + 32 + q * 8);
        dst[3] = *reinterpret_cast<const float4_t*>(p + col + 32 + q * 8 + 4);
    };
    auto loadB = [&](int c) {
#pragma unroll
        for (int i = 0; i < 8; ++i)
            bReg[i] = *reinterpret_cast<const float4_t*>(bg + (size_t)c * 16384 + i * 2048);
    };
    auto storeB = [&](int c) {
        short* d = sB + (c & 1) * 16384 + t * 8;
#pragma unroll
        for (int i = 0; i < 8; ++i)
            *reinterpret_cast<float4_t*>(d + i * 2048) = bReg[i];
    };

    // prologue: chunk 0 into LDS, A(0) and A(1) into regs
    loadB(0);
    loadA(0, aCur);
    loadA(1, aNxt);
    storeB(0);
    __syncthreads();

    for (int k = 0; k < NCHUNK; ++k) {
        // issue next-chunk loads first (they age a full body before the barrier)
        if (k + 1 < NCHUNK) loadB(k + 1);

        // compute chunk k: 2 k-steps x 16 MFMA
        const short* bufr = sB + (k & 1) * 16384;
#pragma unroll
        for (int s = 0; s < 2; ++s) {
            short8 a;
            a[0] = f2bf(aCur[2*s][0]); a[1] = f2bf(aCur[2*s][1]);
            a[2] = f2bf(aCur[2*s][2]); a[3] = f2bf(aCur[2*s][3]);
            a[4] = f2bf(aCur[2*s+1][0]); a[5] = f2bf(aCur[2*s+1][1]);
            a[6] = f2bf(aCur[2*s+1][2]); a[7] = f2bf(aCur[2*s+1][3]);
#pragma unroll
            for (int nb = 0; nb < 16; ++nb) {
                short8 b = *reinterpret_cast<const short8*>(bufr + s * 8192 + nb * 512 + l * 8);
                acc[nb] = __builtin_amdgcn_mfma_f32_16x16x32_bf16(a, b, acc[nb], 0, 0, 0);
            }
        }

        // rotate A and refill the pipeline
#pragma unroll
        for (int i = 0; i < 4; ++i) aCur[i] = aNxt[i];
        if (k + 2 < NCHUNK) loadA(k + 2, aNxt);

        if (k + 1 < NCHUNK) {
            storeB(k + 1);
            __syncthreads();
        }
    }

    // ---- epilogue: per-wave LDS region (reuses B buffers) ----
    __syncthreads();
    float* sG = reinterpret_cast<float*>(sB) + w * 4096;   // 16 KB per wave
#pragma unroll
    for (int nb = 0; nb < 16; ++nb)
#pragma unroll
        for (int r = 0; r < 4; ++r)
            sG[(q * 4 + r) * 256 + nb * 16 + lr] = acc[nb][r];
    __syncthreads();

    const float wo = Wo[l];
    const float bov = bo[0];
    const float b0 = bsum[l];
    const float b1 = bsum[64 + l];
    const float b2 = bsum[128 + l];
    const float b3 = bsum[192 + l];
    float* outH = out + Brows;
    float* outC = outH + (size_t)Brows * 64;

#pragma unroll
    for (int r = 0; r < 16; ++r) {
        size_t grow = (size_t)bm * 64 + w * 16 + r;
        float gi = sG[r * 256 + l]       + b0;
        float gf = sG[r * 256 + 64 + l]  + b1;
        float gg = sG[r * 256 + 128 + l] + b2;
        float go = sG[r * 256 + 192 + l] + b3;
        float i_t = sigmoid_fast(gi);
        float f_t = sigmoid_fast(gf);
        float g_t = tanh_fast(gg);
        float o_t = sigmoid_fast(go);
        float c_t = f_t * cell[grow * 64 + l] + i_t * g_t;
        float h_t = o_t * tanh_fast(c_t);
        outC[grow * 64 + l] = c_t;
        outH[grow * 64 + l] = h_t;
        float v = h_t * wo;
#pragma unroll
        for (int off = 32; off > 0; off >>= 1) v += __shfl_down(v, off);
        if (l == 0) out[grow] = tanh_fast(v + bov);
    }
}

extern "C" void kernel_launch(void* const* d_in, const int* in_sizes, int n_in,
                              void* d_out, int out_size, void* d_ws, size_t ws_size,
                              hipStream_t stream) {
    const float* state  = (const float*)d_in[0];
    const float* action = (const float*)d_in[1];
    const float* hidden = (const float*)d_in[2];
    const float* cell   = (const float*)d_in[3];
    const float* Wi     = (const float*)d_in[4];
    const float* bi     = (const float*)d_in[5];
    const float* Wh     = (const float*)d_in[6];
    const float* bh     = (const float*)d_in[7];
    const float* Wo     = (const float*)d_in[8];
    const float* bo     = (const float*)d_in[9];

    const int Brows = in_sizes[0] / 2048;   // 32768

    short* Wt2  = (short*)d_ws;                                    // 82*8192 bf16
    float* bsum = (float*)((char*)d_ws + (size_t)NSTEP * 8192 * sizeof(short));

    prep_kernel<<<NSTEP, 256, 0, stream>>>(Wi, bi, Wh, bh, Wt2, bsum);
    lstm_kernel<<<Brows / 64, 256, 0, stream>>>(state, action, hidden, cell,
                                                Wt2, bsum, Wo, bo, (float*)d_out, Brows);
}